// Round 1
// 176.097 us; speedup vs baseline: 1.0561x; 1.0561x over previous
//
#include <hip/hip_runtime.h>
#include <hip/hip_bf16.h>

#define B_ 4
#define S_ 2048
#define D_ 1024
#define H_ 16
#define HD 64

typedef __bf16 bf16;
typedef __bf16 bf16x4 __attribute__((ext_vector_type(4)));
typedef __bf16 bf16x8 __attribute__((ext_vector_type(8)));
typedef float f32x4 __attribute__((ext_vector_type(4)));
typedef float f32x16 __attribute__((ext_vector_type(16)));

#define LOG2E 1.4426950408889634f

__device__ inline void gload_lds16(const bf16* g, bf16* l) {
    __builtin_amdgcn_global_load_lds(
        (const __attribute__((address_space(1))) void*)g,
        (__attribute__((address_space(3))) void*)l, 16, 0, 0);
}

// Swizzled bf16-elem index for a [R][64]-bf16 tile (128B rows):
// LDS byte p holds logical (row=p>>7, colb=(p&127)^((row&7)<<4)).
__device__ inline int swz(int row, int colb) {
    return row * 64 + ((colb ^ ((row & 7) << 4)) >> 1);
}

__device__ inline unsigned cvt_pk_bf16(float lo, float hi) {
    unsigned r;
    asm("v_cvt_pk_bf16_f32 %0, %1, %2" : "=v"(r) : "v"(lo), "v"(hi));
    return r;
}

// ---------------- Kernel 1: cast x and pack Wq|Wk|Wv to bf16 ----------------
__global__ void cast_pack_kernel(const float* __restrict__ x,
                                 const float* __restrict__ Wq,
                                 const float* __restrict__ Wk,
                                 const float* __restrict__ Wv,
                                 bf16* __restrict__ Xb, bf16* __restrict__ Wb) {
    const long XN = (long)B_ * S_ * D_;
    const long WN = (long)D_ * D_;
    long i4 = ((long)blockIdx.x * blockDim.x + threadIdx.x) * 4;
    if (i4 < XN) {
        float4 v = *(const float4*)(x + i4);
        bf16* o = Xb + i4;
        o[0] = (bf16)v.x; o[1] = (bf16)v.y; o[2] = (bf16)v.z; o[3] = (bf16)v.w;
    } else {
        long j = i4 - XN;
        if (j < 3 * WN) {
            int which = (int)(j / WN);
            long jj = j - (long)which * WN;
            const float* src = which == 0 ? Wq : which == 1 ? Wk : Wv;
            float4 v = *(const float4*)(src + jj);
            bf16* o = Wb + j;
            o[0] = (bf16)v.x; o[1] = (bf16)v.y; o[2] = (bf16)v.z; o[3] = (bf16)v.w;
        }
    }
}

// ---------------- Kernel 2: fused QKV projection GEMM (unchanged) ----------
#define GM 128
#define GN 128
#define GK 64

__global__ __launch_bounds__(256) void gemm_qkv_kernel(
    const bf16* __restrict__ Xb, const bf16* __restrict__ Wb,
    const float* __restrict__ bq, const float* __restrict__ bk,
    const float* __restrict__ bv,
    bf16* __restrict__ Qg, bf16* __restrict__ Kg, bf16* __restrict__ Vt) {
    __shared__ bf16 SMEM[GM * GK + GN * GK];   // 32 KB; reused by V epilogue
    bf16* As = SMEM;
    bf16* Bs = SMEM + GM * GK;
    const int tid = threadIdx.x;
    const int lane = tid & 63;
    const int wid = tid >> 6;
    const int col = lane & 15, grp = lane >> 4;

    // bijective XCD swizzle: 1536 blocks -> 8 chunks of 192 (8 M-panels each)
    const int id = blockIdx.x;
    const int id2 = (id & 7) * 192 + (id >> 3);
    const int m0 = (id2 / 24) * GM;
    const int n0 = (id2 % 24) * GN;
    const int wr = wid >> 1, wc = wid & 1;

    const f32x4 zf = {0.f, 0.f, 0.f, 0.f};
    f32x4 acc[4][4];
#pragma unroll
    for (int m = 0; m < 4; m++)
#pragma unroll
        for (int n = 0; n < 4; n++) acc[m][n] = zf;

    for (int kt = 0; kt < D_ / GK; ++kt) {
        const int k0 = kt * GK;
#pragma unroll
        for (int i = 0; i < 4; i++) {
            int fl = i * 2048 + wid * 512 + lane * 8;
            int r = fl >> 6, c = fl & 63;
            gload_lds16(Xb + (size_t)(m0 + r) * D_ + k0 + c, As + i * 2048 + wid * 512);
        }
#pragma unroll
        for (int i = 0; i < 4; i++) {
            int fl = i * 2048 + wid * 512 + lane * 8;
            int r = fl >> 6, c = fl & 63;
            gload_lds16(Wb + (size_t)(n0 + r) * D_ + k0 + c, Bs + i * 2048 + wid * 512);
        }
        __syncthreads();
#pragma unroll
        for (int kk = 0; kk < 2; ++kk) {
            bf16x8 a[4], b[4];
#pragma unroll
            for (int m = 0; m < 4; m++)
                a[m] = *(const bf16x8*)(As + (wr * 64 + m * 16 + col) * GK + kk * 32 + grp * 8);
#pragma unroll
            for (int n = 0; n < 4; n++)
                b[n] = *(const bf16x8*)(Bs + (wc * 64 + n * 16 + col) * GK + kk * 32 + grp * 8);
#pragma unroll
            for (int m = 0; m < 4; m++)
#pragma unroll
                for (int n = 0; n < 4; n++)
                    acc[m][n] = __builtin_amdgcn_mfma_f32_16x16x32_bf16(a[m], b[n], acc[m][n], 0, 0, 0);
        }
        __syncthreads();
    }

    const int which = n0 >> 10;   // block-uniform (region = 8 N-tiles)
    if (which == 2) {
        // ---- V: bias, transpose via LDS (swizzled on s), coalesced store ----
        bf16* Vl = SMEM;   // 128(d) x 128(s)
#pragma unroll
        for (int n = 0; n < 4; n++) {
            int dl = wc * 64 + n * 16 + col;
            float bias = bv[(n0 - 2048) + dl];
#pragma unroll
            for (int m = 0; m < 4; m++) {
                bf16x4 pv;
#pragma unroll
                for (int i = 0; i < 4; i++) pv[i] = (bf16)(acc[m][n][i] + bias);
                int sl = wr * 64 + m * 16 + grp * 4;
                *(bf16x4*)(&Vl[dl * 128 + (sl ^ ((dl & 7) << 3))]) = pv;
            }
        }
        __syncthreads();
#pragma unroll
        for (int c0 = 0; c0 < 8; c0++) {
            int c = c0 * 256 + tid;
            int dl = c >> 4, s8 = (c & 15) * 8;
            bf16x8 val = *(const bf16x8*)(&Vl[dl * 128 + (s8 ^ ((dl & 7) << 3))]);
            int s = m0 + s8;
            int b = s >> 11, sl = s & 2047;
            int dglob = (n0 - 2048) + dl;
            int h = dglob >> 6, dd = dglob & 63;
            *(bf16x8*)(&Vt[((size_t)(b * H_ + h) * HD + dd) * S_ + sl]) = val;
        }
    } else {
        const float* bp = which == 0 ? bq : bk;
        bf16* dst = which == 0 ? Qg : Kg;
        const float qsc = which == 0 ? (0.125f * LOG2E) : 1.0f;
#pragma unroll
        for (int n = 0; n < 4; n++) {
            int e = n0 + wc * 64 + n * 16 + col;
            int ee = e & 1023;
            float bias = bp[ee];
            int h = ee >> 6, d = ee & 63;
#pragma unroll
            for (int m = 0; m < 4; m++) {
#pragma unroll
                for (int i = 0; i < 4; i++) {
                    int s = m0 + wr * 64 + m * 16 + grp * 4 + i;
                    int b = s >> 11, sl = s & 2047;
                    dst[((size_t)(b * H_ + h) * S_ + sl) * HD + d] =
                        (bf16)((acc[m][n][i] + bias) * qsc);
                }
            }
        }
    }
}

// ---------------- Kernel 3: flash attention v12 ----------------
// 32x32x16 MFMA, swapped QK^T. P never touches LDS: after QK each lane holds
// S^T[kv][q=lane&31] for 16 kv rows; cvt_pk_bf16 + v_permlane32_swap_b32
// redistributes into the PV B-operand fragment layout (guide T12).
// Denominator = f32 register sum of exp2 values + one shfl_xor(32) at the end
// (ones-MFMA removed). No SM_SHIFT (power-of-2 shift cancels in normalize).
#define KB 64

__global__ __launch_bounds__(512, 4) void attn_kernel(
    const bf16* __restrict__ Qg, const bf16* __restrict__ Kg,
    const bf16* __restrict__ Vt, float* __restrict__ out) {
    __shared__ bf16 Ks[2][64 * 64];    // swizzled [kv][d]
    __shared__ bf16 Vs[2][64 * 64];    // swizzled [d][kv]
    const int tid = threadIdx.x, lane = tid & 63, wid = tid >> 6;
    const int l31 = lane & 31, hi = lane >> 5;

    // XCD swizzle: 512 blocks -> 8 chunks of 64; each XCD owns 8 bh (4MB KV = L2).
    const int id = blockIdx.x;
    const int swzid = (id & 7) * 64 + (id >> 3);
    const int bh = swzid >> 3;            // 8 q-blocks per bh
    const int q0 = (swzid & 7) * 256 + wid * 32;

    const bf16* Kbase = Kg + (size_t)bh * S_ * HD;
    const bf16* Vbase = Vt + (size_t)bh * HD * S_;

    const int r0 = tid >> 3;              // 0..63
    const int cb = ((tid & 7) * 16) ^ ((r0 & 7) << 4);
    const bf16* ksrc = Kbase + (size_t)r0 * HD + (cb >> 1);
    const bf16* vsrc = Vbase + (size_t)r0 * S_ + (cb >> 1);

#define STAGE(bsel, kv0)                                            \
    do {                                                            \
        gload_lds16(ksrc + (size_t)(kv0)*HD, &Ks[bsel][wid * 512]); \
        gload_lds16(vsrc + (kv0), &Vs[bsel][wid * 512]);            \
    } while (0)

    // Q fragments (pre-scaled by 0.125*log2e): B-operand, 4 k-steps of 16
    bf16x8 qa[4];
#pragma unroll
    for (int ks = 0; ks < 4; ks++)
        qa[ks] = *(const bf16x8*)(Qg + ((size_t)bh * S_ + q0 + l31) * HD + ks * 16 + hi * 8);

    const f32x16 z16 = {0.f, 0.f, 0.f, 0.f, 0.f, 0.f, 0.f, 0.f,
                        0.f, 0.f, 0.f, 0.f, 0.f, 0.f, 0.f, 0.f};
    f32x16 o[2];
    o[0] = z16; o[1] = z16;
    f32x4 ls = {0.f, 0.f, 0.f, 0.f};

    int cur = 0;
    STAGE(0, 0);
    __syncthreads();

    for (int t = 0; t < S_ / KB; ++t) {
        if (t < S_ / KB - 1) STAGE(cur ^ 1, (t + 1) * KB);

        // S^T (log2 domain): sc[kvt][r] = S[kv = kvt*32+(r&3)+8*(r>>2)+4*hi][q = q0+l31]
        f32x16 sc[2];
        __builtin_amdgcn_s_setprio(1);
#pragma unroll
        for (int kvt = 0; kvt < 2; kvt++) {
            {
                bf16x8 kb = *(const bf16x8*)(&Ks[cur][swz(kvt * 32 + l31, hi * 16)]);
                sc[kvt] = __builtin_amdgcn_mfma_f32_32x32x16_bf16(kb, qa[0], z16, 0, 0, 0);
            }
#pragma unroll
            for (int ks = 1; ks < 4; ks++) {
                bf16x8 kb = *(const bf16x8*)(&Ks[cur][swz(kvt * 32 + l31, ks * 32 + hi * 16)]);
                sc[kvt] = __builtin_amdgcn_mfma_f32_32x32x16_bf16(kb, qa[ks], sc[kvt], 0, 0, 0);
            }
        }
        __builtin_amdgcn_s_setprio(0);

        // ---- softmax: p = exp2(sc); ls += p; pa via cvt_pk + permlane32_swap ----
        bf16x8 pa[4];
#pragma unroll
        for (int kvt = 0; kvt < 2; kvt++) {
            float p[16];
#pragma unroll
            for (int r = 0; r < 16; r++) p[r] = __builtin_amdgcn_exp2f(sc[kvt][r]);
            f32x4 s0 = {p[0], p[1], p[2], p[3]};
            f32x4 s1 = {p[4], p[5], p[6], p[7]};
            f32x4 s2 = {p[8], p[9], p[10], p[11]};
            f32x4 s3 = {p[12], p[13], p[14], p[15]};
            ls += (s0 + s1) + (s2 + s3);
#pragma unroll
            for (int b = 0; b < 2; b++) {
                // lane hi=0 holds kv' {16b+0..3, 16b+8..11}; hi=1 holds {+4,+12}.
                // After swap: A'={16b+0,1 | 16b+8,9}, B'={16b+4,5 | 16b+12,13} etc.
                unsigned A  = cvt_pk_bf16(p[8 * b + 0], p[8 * b + 1]);
                unsigned Bw = cvt_pk_bf16(p[8 * b + 4], p[8 * b + 5]);
                unsigned C  = cvt_pk_bf16(p[8 * b + 2], p[8 * b + 3]);
                unsigned Dw = cvt_pk_bf16(p[8 * b + 6], p[8 * b + 7]);
                asm("v_permlane32_swap_b32 %0, %1" : "+v"(A), "+v"(Bw));
                asm("v_permlane32_swap_b32 %0, %1" : "+v"(C), "+v"(Dw));
                union { unsigned u[4]; bf16x8 v; } pk;
                pk.u[0] = A; pk.u[1] = C; pk.u[2] = Bw; pk.u[3] = Dw;
                pa[kvt * 2 + b] = pk.v;   // B-operand: P[kv=16*(kvt*2+b)+8*hi+j][q]
            }
        }

        // ---- O^T += V^T P ----
        __builtin_amdgcn_s_setprio(1);
#pragma unroll
        for (int ks2 = 0; ks2 < 4; ks2++) {
#pragma unroll
            for (int dt = 0; dt < 2; dt++) {
                bf16x8 vb = *(const bf16x8*)(&Vs[cur][swz(dt * 32 + l31, ks2 * 32 + hi * 16)]);
                o[dt] = __builtin_amdgcn_mfma_f32_32x32x16_bf16(vb, pa[ks2], o[dt], 0, 0, 0);
            }
        }
        __builtin_amdgcn_s_setprio(0);

        __syncthreads();
        cur ^= 1;
    }

    // denominator: own-half sum + other-half sum (same q = lane&31)
    float denom = ls[0] + ls[1] + ls[2] + ls[3];
    denom += __shfl_xor(denom, 32);
    float inv = 1.f / denom;

    int b = bh >> 4, h = bh & 15;
    int q = q0 + l31;
    float* obase = out + ((size_t)(b * S_ + q)) * D_ + h * HD;
#pragma unroll
    for (int dt = 0; dt < 2; dt++)
#pragma unroll
        for (int g = 0; g < 4; g++) {
            f32x4 r = {o[dt][4 * g + 0] * inv, o[dt][4 * g + 1] * inv,
                       o[dt][4 * g + 2] * inv, o[dt][4 * g + 3] * inv};
            *(f32x4*)(obase + dt * 32 + 8 * g + 4 * hi) = r;
        }
#undef STAGE
}

extern "C" void kernel_launch(void* const* d_in, const int* in_sizes, int n_in,
                              void* d_out, int out_size, void* d_ws, size_t ws_size,
                              hipStream_t stream) {
    const float* x  = (const float*)d_in[0];
    const float* Wq = (const float*)d_in[1];
    const float* bq = (const float*)d_in[2];
    const float* Wk = (const float*)d_in[3];
    const float* bk = (const float*)d_in[4];
    const float* Wv = (const float*)d_in[5];
    const float* bv = (const float*)d_in[6];
    float* out = (float*)d_out;

    bf16* ws = (bf16*)d_ws;
    bf16* Xb = ws;
    bf16* Wb = Xb + (size_t)B_ * S_ * D_;
    bf16* Qg = Wb + (size_t)3 * D_ * D_;
    bf16* Kg = Qg + (size_t)B_ * S_ * D_;
    bf16* Vt = Kg + (size_t)B_ * S_ * D_;

    hipLaunchKernelGGL(cast_pack_kernel,
                       dim3((B_ * S_ * D_ + 3 * D_ * D_) / (4 * 256)), dim3(256), 0, stream,
                       x, Wq, Wk, Wv, Xb, Wb);
    hipLaunchKernelGGL(gemm_qkv_kernel, dim3(24 * 64), dim3(256), 0, stream,
                       Xb, Wb, bq, bk, bv, Qg, Kg, Vt);
    hipLaunchKernelGGL(attn_kernel, dim3(512), dim3(512), 0, stream,
                       Qg, Kg, Vt, out);
}

// Round 3
// 159.440 us; speedup vs baseline: 1.1664x; 1.1045x over previous
//
#include <hip/hip_runtime.h>
#include <hip/hip_bf16.h>

#define B_ 4
#define S_ 2048
#define D_ 1024
#define H_ 16
#define HD 64

typedef __bf16 bf16;
typedef __bf16 bf16x4 __attribute__((ext_vector_type(4)));
typedef __bf16 bf16x8 __attribute__((ext_vector_type(8)));
typedef float f32x4 __attribute__((ext_vector_type(4)));
typedef float f32x16 __attribute__((ext_vector_type(16)));

#define LOG2E 1.4426950408889634f

__device__ inline void gload_lds16(const bf16* g, bf16* l) {
    __builtin_amdgcn_global_load_lds(
        (const __attribute__((address_space(1))) void*)g,
        (__attribute__((address_space(3))) void*)l, 16, 0, 0);
}

// Swizzled bf16-elem index for a [R][64]-bf16 tile (128B rows):
// LDS byte p holds logical (row=p>>7, colb=(p&127)^((row&7)<<4)).
__device__ inline int swz(int row, int colb) {
    return row * 64 + ((colb ^ ((row & 7) << 4)) >> 1);
}

__device__ inline unsigned cvt_pk_bf16(float lo, float hi) {
    unsigned r;
    asm("v_cvt_pk_bf16_f32 %0, %1, %2" : "=v"(r) : "v"(lo), "v"(hi));
    return r;
}

// ---------------- Kernel 1: cast x and pack Wq|Wk|Wv to bf16 ----------------
__global__ void cast_pack_kernel(const float* __restrict__ x,
                                 const float* __restrict__ Wq,
                                 const float* __restrict__ Wk,
                                 const float* __restrict__ Wv,
                                 bf16* __restrict__ Xb, bf16* __restrict__ Wb) {
    const long XN = (long)B_ * S_ * D_;
    const long WN = (long)D_ * D_;
    long i4 = ((long)blockIdx.x * blockDim.x + threadIdx.x) * 4;
    if (i4 < XN) {
        float4 v = *(const float4*)(x + i4);
        bf16* o = Xb + i4;
        o[0] = (bf16)v.x; o[1] = (bf16)v.y; o[2] = (bf16)v.z; o[3] = (bf16)v.w;
    } else {
        long j = i4 - XN;
        if (j < 3 * WN) {
            int which = (int)(j / WN);
            long jj = j - (long)which * WN;
            const float* src = which == 0 ? Wq : which == 1 ? Wk : Wv;
            float4 v = *(const float4*)(src + jj);
            bf16* o = Wb + j;
            o[0] = (bf16)v.x; o[1] = (bf16)v.y; o[2] = (bf16)v.z; o[3] = (bf16)v.w;
        }
    }
}

// ---------------- Kernel 2: QKV projection GEMM, 8-wave deep-phase ----------
// BM=128 x BN=256 x BK=64. 8 waves (2M x 4N), 64x64 per wave. Double-buffered
// swizzled LDS (As 2x16KB + Bs 2x32KB = 96KB); 2 phases per K-tile: {8 ds_read
// + 3 stage-issues -> raw barrier -> lgkmcnt(0) -> 16 MFMA}; vmcnt drained
// once per tile (T3+T4), st-swizzle (T2), setprio (T5), XCD swizzle (T1).
#define TM 128
#define TN 256
#define TK 64

__global__ __launch_bounds__(512, 2) void gemm_qkv_kernel(
    const bf16* __restrict__ Xb, const bf16* __restrict__ Wb,
    const float* __restrict__ bq, const float* __restrict__ bk,
    const float* __restrict__ bv,
    bf16* __restrict__ Qg, bf16* __restrict__ Kg, bf16* __restrict__ Vt) {
    __shared__ bf16 SMEM[49152];                   // 96 KB (was 48KB: OOB bug)
    bf16* As = SMEM;                               // As[c] at c*8192   (2x16KB)
    bf16* Bs = SMEM + 16384;                       // Bs[c] at c*16384  (2x32KB)
    const int tid = threadIdx.x;
    const int lane = tid & 63;
    const int wid = tid >> 6;
    const int col = lane & 15, grp = lane >> 4;
    const int wr = wid >> 2, wc = wid & 3;         // 2M x 4N wave grid

    // bijective XCD swizzle: 768 blocks -> 8 chunks of 96 (m-major, n-minor)
    const int id = blockIdx.x;
    const int id2 = (id & 7) * 96 + (id >> 3);
    const int m0 = (id2 / 12) * TM;
    const int n0 = (id2 % 12) * TN;

    // staging addresses: round j covers rows j*64 + (tid>>3); 16B per lane,
    // source col pre-swizzled so linear LDS + swz() reads line up (rule 21).
    const int r8 = tid >> 3;                       // 0..63
    const int cbs = ((tid & 7) * 16) ^ ((r8 & 7) << 4);
    const bf16* asrc = Xb + (size_t)(m0 + r8) * D_ + (cbs >> 1);
    const bf16* bsrc = Wb + (size_t)(n0 + r8) * D_ + (cbs >> 1);

#define STAGE_A(c, kt, j) \
    gload_lds16(asrc + (size_t)(j) * 64 * D_ + (kt) * TK, As + (c) * 8192 + (j) * 4096 + wid * 512)
#define STAGE_B(c, kt, j) \
    gload_lds16(bsrc + (size_t)(j) * 64 * D_ + (kt) * TK, Bs + (c) * 16384 + (j) * 4096 + wid * 512)

    const f32x4 zf = {0.f, 0.f, 0.f, 0.f};
    f32x4 acc[4][4];
#pragma unroll
    for (int m = 0; m < 4; m++)
#pragma unroll
        for (int n = 0; n < 4; n++) acc[m][n] = zf;

    // prologue: stage tile 0 into buf 0, drain, barrier
    STAGE_A(0, 0, 0); STAGE_A(0, 0, 1);
    STAGE_B(0, 0, 0); STAGE_B(0, 0, 1); STAGE_B(0, 0, 2); STAGE_B(0, 0, 3);
    asm volatile("s_waitcnt vmcnt(0)");
    __builtin_amdgcn_s_barrier();

    int c = 0;
#pragma unroll 1
    for (int kt = 0; kt < D_ / TK; ++kt) {
        const bf16* Ac = As + c * 8192;
        const bf16* Bc = Bs + c * 16384;
        // ---- phase 0 (kk = 0) ----
        {
            bf16x8 a[4], b[4];
#pragma unroll
            for (int m = 0; m < 4; m++)
                a[m] = *(const bf16x8*)(Ac + swz(wr * 64 + m * 16 + col, grp * 16));
#pragma unroll
            for (int n = 0; n < 4; n++)
                b[n] = *(const bf16x8*)(Bc + swz(wc * 64 + n * 16 + col, grp * 16));
            if (kt < D_ / TK - 1) {
                STAGE_A(c ^ 1, kt + 1, 0); STAGE_A(c ^ 1, kt + 1, 1);
                STAGE_B(c ^ 1, kt + 1, 0);
            }
            __builtin_amdgcn_s_barrier();
            asm volatile("s_waitcnt lgkmcnt(0)");
            __builtin_amdgcn_sched_barrier(0);
            __builtin_amdgcn_s_setprio(1);
#pragma unroll
            for (int m = 0; m < 4; m++)
#pragma unroll
                for (int n = 0; n < 4; n++)
                    acc[m][n] = __builtin_amdgcn_mfma_f32_16x16x32_bf16(a[m], b[n], acc[m][n], 0, 0, 0);
            __builtin_amdgcn_s_setprio(0);
            __builtin_amdgcn_s_barrier();
        }
        // ---- phase 1 (kk = 1) ----
        {
            bf16x8 a[4], b[4];
#pragma unroll
            for (int m = 0; m < 4; m++)
                a[m] = *(const bf16x8*)(Ac + swz(wr * 64 + m * 16 + col, 64 + grp * 16));
#pragma unroll
            for (int n = 0; n < 4; n++)
                b[n] = *(const bf16x8*)(Bc + swz(wc * 64 + n * 16 + col, 64 + grp * 16));
            if (kt < D_ / TK - 1) {
                STAGE_B(c ^ 1, kt + 1, 1); STAGE_B(c ^ 1, kt + 1, 2); STAGE_B(c ^ 1, kt + 1, 3);
            }
            __builtin_amdgcn_s_barrier();
            asm volatile("s_waitcnt lgkmcnt(0)");
            __builtin_amdgcn_sched_barrier(0);
            __builtin_amdgcn_s_setprio(1);
#pragma unroll
            for (int m = 0; m < 4; m++)
#pragma unroll
                for (int n = 0; n < 4; n++)
                    acc[m][n] = __builtin_amdgcn_mfma_f32_16x16x32_bf16(a[m], b[n], acc[m][n], 0, 0, 0);
            __builtin_amdgcn_s_setprio(0);
            asm volatile("s_waitcnt vmcnt(0)");   // tile boundary: next tile's data ready
            __builtin_amdgcn_s_barrier();
        }
        c ^= 1;
    }
#undef STAGE_A
#undef STAGE_B

    const int which = n0 >> 10;   // block-uniform (BN=256 divides regions)
    if (which == 2) {
        // ---- V: bias, transpose via LDS (swizzled on s), coalesced store ----
        __syncthreads();
        bf16* Vl = SMEM;   // 256(d) x 128(s) = 64 KB
#pragma unroll
        for (int n = 0; n < 4; n++) {
            int dl = wc * 64 + n * 16 + col;
            float bias = bv[(n0 - 2048) + dl];
#pragma unroll
            for (int m = 0; m < 4; m++) {
                bf16x4 pv;
#pragma unroll
                for (int i = 0; i < 4; i++) pv[i] = (bf16)(acc[m][n][i] + bias);
                int sl = wr * 64 + m * 16 + grp * 4;
                *(bf16x4*)(&Vl[dl * 128 + (sl ^ ((dl & 7) << 3))]) = pv;
            }
        }
        __syncthreads();
#pragma unroll
        for (int c0 = 0; c0 < 8; c0++) {
            int cc = c0 * 512 + tid;
            int dl = cc >> 4, s8 = (cc & 15) * 8;
            bf16x8 val = *(const bf16x8*)(&Vl[dl * 128 + (s8 ^ ((dl & 7) << 3))]);
            int s = m0 + s8;
            int b = s >> 11, sl = s & 2047;
            int dglob = (n0 - 2048) + dl;
            int h = dglob >> 6, dd = dglob & 63;
            *(bf16x8*)(&Vt[((size_t)(b * H_ + h) * HD + dd) * S_ + sl]) = val;
        }
    } else {
        const float* bp = which == 0 ? bq : bk;
        bf16* dst = which == 0 ? Qg : Kg;
        const float qsc = which == 0 ? (0.125f * LOG2E) : 1.0f;
#pragma unroll
        for (int n = 0; n < 4; n++) {
            int e = n0 + wc * 64 + n * 16 + col;
            int ee = e & 1023;
            float bias = bp[ee];
            int h = ee >> 6, d = ee & 63;
#pragma unroll
            for (int m = 0; m < 4; m++) {
#pragma unroll
                for (int i = 0; i < 4; i++) {
                    int s = m0 + wr * 64 + m * 16 + grp * 4 + i;
                    int b = s >> 11, sl = s & 2047;
                    dst[((size_t)(b * H_ + h) * S_ + sl) * HD + d] =
                        (bf16)((acc[m][n][i] + bias) * qsc);
                }
            }
        }
    }
}

// ---------------- Kernel 3: flash attention v12 (unchanged) ----------------
// 32x32x16 MFMA, swapped QK^T. P never touches LDS: after QK each lane holds
// S^T[kv][q=lane&31] for 16 kv rows; cvt_pk_bf16 + v_permlane32_swap_b32
// redistributes into the PV B-operand fragment layout (guide T12).
#define KB 64

__global__ __launch_bounds__(512, 4) void attn_kernel(
    const bf16* __restrict__ Qg, const bf16* __restrict__ Kg,
    const bf16* __restrict__ Vt, float* __restrict__ out) {
    __shared__ bf16 Ks[2][64 * 64];    // swizzled [kv][d]
    __shared__ bf16 Vs[2][64 * 64];    // swizzled [d][kv]
    const int tid = threadIdx.x, lane = tid & 63, wid = tid >> 6;
    const int l31 = lane & 31, hi = lane >> 5;

    // XCD swizzle: 512 blocks -> 8 chunks of 64; each XCD owns 8 bh (4MB KV = L2).
    const int id = blockIdx.x;
    const int swzid = (id & 7) * 64 + (id >> 3);
    const int bh = swzid >> 3;            // 8 q-blocks per bh
    const int q0 = (swzid & 7) * 256 + wid * 32;

    const bf16* Kbase = Kg + (size_t)bh * S_ * HD;
    const bf16* Vbase = Vt + (size_t)bh * HD * S_;

    const int r0 = tid >> 3;              // 0..63
    const int cb = ((tid & 7) * 16) ^ ((r0 & 7) << 4);
    const bf16* ksrc = Kbase + (size_t)r0 * HD + (cb >> 1);
    const bf16* vsrc = Vbase + (size_t)r0 * S_ + (cb >> 1);

#define STAGE(bsel, kv0)                                            \
    do {                                                            \
        gload_lds16(ksrc + (size_t)(kv0)*HD, &Ks[bsel][wid * 512]); \
        gload_lds16(vsrc + (kv0), &Vs[bsel][wid * 512]);            \
    } while (0)

    // Q fragments (pre-scaled by 0.125*log2e): B-operand, 4 k-steps of 16
    bf16x8 qa[4];
#pragma unroll
    for (int ks = 0; ks < 4; ks++)
        qa[ks] = *(const bf16x8*)(Qg + ((size_t)bh * S_ + q0 + l31) * HD + ks * 16 + hi * 8);

    const f32x16 z16 = {0.f, 0.f, 0.f, 0.f, 0.f, 0.f, 0.f, 0.f,
                        0.f, 0.f, 0.f, 0.f, 0.f, 0.f, 0.f, 0.f};
    f32x16 o[2];
    o[0] = z16; o[1] = z16;
    f32x4 ls = {0.f, 0.f, 0.f, 0.f};

    int cur = 0;
    STAGE(0, 0);
    __syncthreads();

    for (int t = 0; t < S_ / KB; ++t) {
        if (t < S_ / KB - 1) STAGE(cur ^ 1, (t + 1) * KB);

        // S^T (log2 domain): sc[kvt][r] = S[kv = kvt*32+(r&3)+8*(r>>2)+4*hi][q = q0+l31]
        f32x16 sc[2];
        __builtin_amdgcn_s_setprio(1);
#pragma unroll
        for (int kvt = 0; kvt < 2; kvt++) {
            {
                bf16x8 kb = *(const bf16x8*)(&Ks[cur][swz(kvt * 32 + l31, hi * 16)]);
                sc[kvt] = __builtin_amdgcn_mfma_f32_32x32x16_bf16(kb, qa[0], z16, 0, 0, 0);
            }
#pragma unroll
            for (int ks = 1; ks < 4; ks++) {
                bf16x8 kb = *(const bf16x8*)(&Ks[cur][swz(kvt * 32 + l31, ks * 32 + hi * 16)]);
                sc[kvt] = __builtin_amdgcn_mfma_f32_32x32x16_bf16(kb, qa[ks], sc[kvt], 0, 0, 0);
            }
        }
        __builtin_amdgcn_s_setprio(0);

        // ---- softmax: p = exp2(sc); ls += p; pa via cvt_pk + permlane32_swap ----
        bf16x8 pa[4];
#pragma unroll
        for (int kvt = 0; kvt < 2; kvt++) {
            float p[16];
#pragma unroll
            for (int r = 0; r < 16; r++) p[r] = __builtin_amdgcn_exp2f(sc[kvt][r]);
            f32x4 s0 = {p[0], p[1], p[2], p[3]};
            f32x4 s1 = {p[4], p[5], p[6], p[7]};
            f32x4 s2 = {p[8], p[9], p[10], p[11]};
            f32x4 s3 = {p[12], p[13], p[14], p[15]};
            ls += (s0 + s1) + (s2 + s3);
#pragma unroll
            for (int b = 0; b < 2; b++) {
                unsigned A  = cvt_pk_bf16(p[8 * b + 0], p[8 * b + 1]);
                unsigned Bw = cvt_pk_bf16(p[8 * b + 4], p[8 * b + 5]);
                unsigned C  = cvt_pk_bf16(p[8 * b + 2], p[8 * b + 3]);
                unsigned Dw = cvt_pk_bf16(p[8 * b + 6], p[8 * b + 7]);
                asm("v_permlane32_swap_b32 %0, %1" : "+v"(A), "+v"(Bw));
                asm("v_permlane32_swap_b32 %0, %1" : "+v"(C), "+v"(Dw));
                union { unsigned u[4]; bf16x8 v; } pk;
                pk.u[0] = A; pk.u[1] = C; pk.u[2] = Bw; pk.u[3] = Dw;
                pa[kvt * 2 + b] = pk.v;   // B-operand: P[kv=16*(kvt*2+b)+8*hi+j][q]
            }
        }

        // ---- O^T += V^T P ----
        __builtin_amdgcn_s_setprio(1);
#pragma unroll
        for (int ks2 = 0; ks2 < 4; ks2++) {
#pragma unroll
            for (int dt = 0; dt < 2; dt++) {
                bf16x8 vb = *(const bf16x8*)(&Vs[cur][swz(dt * 32 + l31, ks2 * 32 + hi * 16)]);
                o[dt] = __builtin_amdgcn_mfma_f32_32x32x16_bf16(vb, pa[ks2], o[dt], 0, 0, 0);
            }
        }
        __builtin_amdgcn_s_setprio(0);

        __syncthreads();
        cur ^= 1;
    }

    // denominator: own-half sum + other-half sum (same q = lane&31)
    float denom = ls[0] + ls[1] + ls[2] + ls[3];
    denom += __shfl_xor(denom, 32);
    float inv = 1.f / denom;

    int b = bh >> 4, h = bh & 15;
    int q = q0 + l31;
    float* obase = out + ((size_t)(b * S_ + q)) * D_ + h * HD;
#pragma unroll
    for (int dt = 0; dt < 2; dt++)
#pragma unroll
        for (int g = 0; g < 4; g++) {
            f32x4 r = {o[dt][4 * g + 0] * inv, o[dt][4 * g + 1] * inv,
                       o[dt][4 * g + 2] * inv, o[dt][4 * g + 3] * inv};
            *(f32x4*)(obase + dt * 32 + 8 * g + 4 * hi) = r;
        }
#undef STAGE
}

extern "C" void kernel_launch(void* const* d_in, const int* in_sizes, int n_in,
                              void* d_out, int out_size, void* d_ws, size_t ws_size,
                              hipStream_t stream) {
    const float* x  = (const float*)d_in[0];
    const float* Wq = (const float*)d_in[1];
    const float* bq = (const float*)d_in[2];
    const float* Wk = (const float*)d_in[3];
    const float* bk = (const float*)d_in[4];
    const float* Wv = (const float*)d_in[5];
    const float* bv = (const float*)d_in[6];
    float* out = (float*)d_out;

    bf16* ws = (bf16*)d_ws;
    bf16* Xb = ws;
    bf16* Wb = Xb + (size_t)B_ * S_ * D_;
    bf16* Qg = Wb + (size_t)3 * D_ * D_;
    bf16* Kg = Qg + (size_t)B_ * S_ * D_;
    bf16* Vt = Kg + (size_t)B_ * S_ * D_;

    hipLaunchKernelGGL(cast_pack_kernel,
                       dim3((B_ * S_ * D_ + 3 * D_ * D_) / (4 * 256)), dim3(256), 0, stream,
                       x, Wq, Wk, Wv, Xb, Wb);
    hipLaunchKernelGGL(gemm_qkv_kernel, dim3(64 * 12), dim3(512), 0, stream,
                       Xb, Wb, bq, bk, bv, Qg, Kg, Vt);
    hipLaunchKernelGGL(attn_kernel, dim3(512), dim3(512), 0, stream,
                       Qg, Kg, Vt, out);
}

// Round 4
// 158.321 us; speedup vs baseline: 1.1747x; 1.0071x over previous
//
#include <hip/hip_runtime.h>
#include <hip/hip_bf16.h>

#define B_ 4
#define S_ 2048
#define D_ 1024
#define H_ 16
#define HD 64

typedef __bf16 bf16;
typedef __bf16 bf16x4 __attribute__((ext_vector_type(4)));
typedef __bf16 bf16x8 __attribute__((ext_vector_type(8)));
typedef float f32x4 __attribute__((ext_vector_type(4)));
typedef float f32x16 __attribute__((ext_vector_type(16)));

#define LOG2E 1.4426950408889634f

__device__ inline void gload_lds16(const bf16* g, bf16* l) {
    __builtin_amdgcn_global_load_lds(
        (const __attribute__((address_space(1))) void*)g,
        (__attribute__((address_space(3))) void*)l, 16, 0, 0);
}

// Swizzled bf16-elem index for a [R][64]-bf16 tile (128B rows):
// LDS byte p holds logical (row=p>>7, colb=(p&127)^((row&7)<<4)).
__device__ inline int swz(int row, int colb) {
    return row * 64 + ((colb ^ ((row & 7) << 4)) >> 1);
}

__device__ inline unsigned cvt_pk_bf16(float lo, float hi) {
    unsigned r;
    asm("v_cvt_pk_bf16_f32 %0, %1, %2" : "=v"(r) : "v"(lo), "v"(hi));
    return r;
}

// ---------------- Kernel 1: cast x and pack Wq|Wk|Wv to bf16 ----------------
__global__ void cast_pack_kernel(const float* __restrict__ x,
                                 const float* __restrict__ Wq,
                                 const float* __restrict__ Wk,
                                 const float* __restrict__ Wv,
                                 bf16* __restrict__ Xb, bf16* __restrict__ Wb) {
    const long XN = (long)B_ * S_ * D_;
    const long WN = (long)D_ * D_;
    long i4 = ((long)blockIdx.x * blockDim.x + threadIdx.x) * 4;
    if (i4 < XN) {
        float4 v = *(const float4*)(x + i4);
        bf16* o = Xb + i4;
        o[0] = (bf16)v.x; o[1] = (bf16)v.y; o[2] = (bf16)v.z; o[3] = (bf16)v.w;
    } else {
        long j = i4 - XN;
        if (j < 3 * WN) {
            int which = (int)(j / WN);
            long jj = j - (long)which * WN;
            const float* src = which == 0 ? Wq : which == 1 ? Wk : Wv;
            float4 v = *(const float4*)(src + jj);
            bf16* o = Wb + j;
            o[0] = (bf16)v.x; o[1] = (bf16)v.y; o[2] = (bf16)v.z; o[3] = (bf16)v.w;
        }
    }
}

// ---------------- Kernel 2: QKV projection GEMM, 8-wave deep-phase ----------
// BM=128 x BN=256 x BK=64. 8 waves (2M x 4N), 64x64 per wave. Double-buffered
// swizzled LDS (As 2x16KB + Bs 2x32KB = 96KB); 2 phases per K-tile: {8 ds_read
// + 3 stage-issues -> raw barrier -> lgkmcnt(0) -> 16 MFMA}; vmcnt drained
// once per tile (T3+T4), st-swizzle (T2), setprio (T5), XCD swizzle (T1).
#define TM 128
#define TN 256
#define TK 64

__global__ __launch_bounds__(512, 2) void gemm_qkv_kernel(
    const bf16* __restrict__ Xb, const bf16* __restrict__ Wb,
    const float* __restrict__ bq, const float* __restrict__ bk,
    const float* __restrict__ bv,
    bf16* __restrict__ Qg, bf16* __restrict__ Kg, bf16* __restrict__ Vt) {
    __shared__ bf16 SMEM[49152];                   // 96 KB
    bf16* As = SMEM;                               // As[c] at c*8192   (2x16KB)
    bf16* Bs = SMEM + 16384;                       // Bs[c] at c*16384  (2x32KB)
    const int tid = threadIdx.x;
    const int lane = tid & 63;
    const int wid = tid >> 6;
    const int col = lane & 15, grp = lane >> 4;
    const int wr = wid >> 2, wc = wid & 3;         // 2M x 4N wave grid

    // bijective XCD swizzle: 768 blocks -> 8 chunks of 96 (m-major, n-minor)
    const int id = blockIdx.x;
    const int id2 = (id & 7) * 96 + (id >> 3);
    const int m0 = (id2 / 12) * TM;
    const int n0 = (id2 % 12) * TN;

    // staging addresses: round j covers rows j*64 + (tid>>3); 16B per lane,
    // source col pre-swizzled so linear LDS + swz() reads line up (rule 21).
    const int r8 = tid >> 3;                       // 0..63
    const int cbs = ((tid & 7) * 16) ^ ((r8 & 7) << 4);
    const bf16* asrc = Xb + (size_t)(m0 + r8) * D_ + (cbs >> 1);
    const bf16* bsrc = Wb + (size_t)(n0 + r8) * D_ + (cbs >> 1);

#define STAGE_A(c, kt, j) \
    gload_lds16(asrc + (size_t)(j) * 64 * D_ + (kt) * TK, As + (c) * 8192 + (j) * 4096 + wid * 512)
#define STAGE_B(c, kt, j) \
    gload_lds16(bsrc + (size_t)(j) * 64 * D_ + (kt) * TK, Bs + (c) * 16384 + (j) * 4096 + wid * 512)

    const f32x4 zf = {0.f, 0.f, 0.f, 0.f};
    f32x4 acc[4][4];
#pragma unroll
    for (int m = 0; m < 4; m++)
#pragma unroll
        for (int n = 0; n < 4; n++) acc[m][n] = zf;

    // prologue: stage tile 0 into buf 0, drain, barrier
    STAGE_A(0, 0, 0); STAGE_A(0, 0, 1);
    STAGE_B(0, 0, 0); STAGE_B(0, 0, 1); STAGE_B(0, 0, 2); STAGE_B(0, 0, 3);
    asm volatile("s_waitcnt vmcnt(0)");
    __builtin_amdgcn_s_barrier();

    int c = 0;
#pragma unroll 1
    for (int kt = 0; kt < D_ / TK; ++kt) {
        const bf16* Ac = As + c * 8192;
        const bf16* Bc = Bs + c * 16384;
        // ---- phase 0 (kk = 0) ----
        {
            bf16x8 a[4], b[4];
#pragma unroll
            for (int m = 0; m < 4; m++)
                a[m] = *(const bf16x8*)(Ac + swz(wr * 64 + m * 16 + col, grp * 16));
#pragma unroll
            for (int n = 0; n < 4; n++)
                b[n] = *(const bf16x8*)(Bc + swz(wc * 64 + n * 16 + col, grp * 16));
            if (kt < D_ / TK - 1) {
                STAGE_A(c ^ 1, kt + 1, 0); STAGE_A(c ^ 1, kt + 1, 1);
                STAGE_B(c ^ 1, kt + 1, 0);
            }
            __builtin_amdgcn_s_barrier();
            asm volatile("s_waitcnt lgkmcnt(0)");
            __builtin_amdgcn_sched_barrier(0);
            __builtin_amdgcn_s_setprio(1);
#pragma unroll
            for (int m = 0; m < 4; m++)
#pragma unroll
                for (int n = 0; n < 4; n++)
                    acc[m][n] = __builtin_amdgcn_mfma_f32_16x16x32_bf16(a[m], b[n], acc[m][n], 0, 0, 0);
            __builtin_amdgcn_s_setprio(0);
            __builtin_amdgcn_s_barrier();
        }
        // ---- phase 1 (kk = 1) ----
        {
            bf16x8 a[4], b[4];
#pragma unroll
            for (int m = 0; m < 4; m++)
                a[m] = *(const bf16x8*)(Ac + swz(wr * 64 + m * 16 + col, 64 + grp * 16));
#pragma unroll
            for (int n = 0; n < 4; n++)
                b[n] = *(const bf16x8*)(Bc + swz(wc * 64 + n * 16 + col, 64 + grp * 16));
            if (kt < D_ / TK - 1) {
                STAGE_B(c ^ 1, kt + 1, 1); STAGE_B(c ^ 1, kt + 1, 2); STAGE_B(c ^ 1, kt + 1, 3);
            }
            __builtin_amdgcn_s_barrier();
            asm volatile("s_waitcnt lgkmcnt(0)");
            __builtin_amdgcn_sched_barrier(0);
            __builtin_amdgcn_s_setprio(1);
#pragma unroll
            for (int m = 0; m < 4; m++)
#pragma unroll
                for (int n = 0; n < 4; n++)
                    acc[m][n] = __builtin_amdgcn_mfma_f32_16x16x32_bf16(a[m], b[n], acc[m][n], 0, 0, 0);
            __builtin_amdgcn_s_setprio(0);
            asm volatile("s_waitcnt vmcnt(0)");   // tile boundary: next tile's data ready
            __builtin_amdgcn_s_barrier();
        }
        c ^= 1;
    }
#undef STAGE_A
#undef STAGE_B

    const int which = n0 >> 10;   // block-uniform (BN=256 divides regions)
    if (which == 2) {
        // ---- V: bias, transpose via LDS (swizzled on s), coalesced store ----
        __syncthreads();
        bf16* Vl = SMEM;   // 256(d) x 128(s) = 64 KB
#pragma unroll
        for (int n = 0; n < 4; n++) {
            int dl = wc * 64 + n * 16 + col;
            float bias = bv[(n0 - 2048) + dl];
#pragma unroll
            for (int m = 0; m < 4; m++) {
                bf16x4 pv;
#pragma unroll
                for (int i = 0; i < 4; i++) pv[i] = (bf16)(acc[m][n][i] + bias);
                int sl = wr * 64 + m * 16 + grp * 4;
                *(bf16x4*)(&Vl[dl * 128 + (sl ^ ((dl & 7) << 3))]) = pv;
            }
        }
        __syncthreads();
#pragma unroll
        for (int c0 = 0; c0 < 8; c0++) {
            int cc = c0 * 512 + tid;
            int dl = cc >> 4, s8 = (cc & 15) * 8;
            bf16x8 val = *(const bf16x8*)(&Vl[dl * 128 + (s8 ^ ((dl & 7) << 3))]);
            int s = m0 + s8;
            int b = s >> 11, sl = s & 2047;
            int dglob = (n0 - 2048) + dl;
            int h = dglob >> 6, dd = dglob & 63;
            *(bf16x8*)(&Vt[((size_t)(b * H_ + h) * HD + dd) * S_ + sl]) = val;
        }
    } else {
        const float* bp = which == 0 ? bq : bk;
        bf16* dst = which == 0 ? Qg : Kg;
        const float qsc = which == 0 ? (0.125f * LOG2E) : 1.0f;
#pragma unroll
        for (int n = 0; n < 4; n++) {
            int e = n0 + wc * 64 + n * 16 + col;
            int ee = e & 1023;
            float bias = bp[ee];
            int h = ee >> 6, d = ee & 63;
#pragma unroll
            for (int m = 0; m < 4; m++) {
#pragma unroll
                for (int i = 0; i < 4; i++) {
                    int s = m0 + wr * 64 + m * 16 + grp * 4 + i;
                    int b = s >> 11, sl = s & 2047;
                    dst[((size_t)(b * H_ + h) * S_ + sl) * HD + d] =
                        (bf16)((acc[m][n][i] + bias) * qsc);
                }
            }
        }
    }
}

// ---------------- Kernel 3: flash attention v13 ----------------
// 4 waves x 64 q-rows each (2 qs sub-tiles of 32). K/V fragments read from
// LDS ONCE per wave and shared by both qs streams (halves ds_read per FLOP);
// PV(qs=0) MFMAs overlap exp2/pack(qs=1) VALU within the wave. P stays in
// registers (cvt_pk + permlane32_swap, T12). No max tracking (fixed domain).
#define KB 64

__global__ __launch_bounds__(256, 2) void attn_kernel(
    const bf16* __restrict__ Qg, const bf16* __restrict__ Kg,
    const bf16* __restrict__ Vt, float* __restrict__ out) {
    __shared__ bf16 Ks[2][64 * 64];    // swizzled [kv][d]
    __shared__ bf16 Vs[2][64 * 64];    // swizzled [d][kv]
    const int tid = threadIdx.x, lane = tid & 63, wid = tid >> 6;
    const int l31 = lane & 31, hi = lane >> 5;

    // XCD swizzle: 512 blocks -> 8 chunks of 64; each XCD owns 8 bh (4MB KV = L2).
    const int id = blockIdx.x;
    const int swzid = (id & 7) * 64 + (id >> 3);
    const int bh = swzid >> 3;                 // 8 q-blocks of 256 per bh
    const int q0w = (swzid & 7) * 256 + wid * 64;   // 64 q-rows per wave

    const bf16* Kbase = Kg + (size_t)bh * S_ * HD;
    const bf16* Vbase = Vt + (size_t)bh * HD * S_;

    // staging: 256 threads, 16B/lane; issue j covers rows j*32 + (tid>>3)
    const int r0 = tid >> 3;              // 0..31
    const int cb = ((tid & 7) * 16) ^ ((r0 & 7) << 4);
    const bf16* ksrc = Kbase + (size_t)r0 * HD + (cb >> 1);
    const bf16* vsrc = Vbase + (size_t)r0 * S_ + (cb >> 1);

#define STAGE(bsel, kv0)                                                       \
    do {                                                                       \
        gload_lds16(ksrc + (size_t)(kv0)*HD,        &Ks[bsel][wid * 512]);     \
        gload_lds16(ksrc + (size_t)((kv0) + 32)*HD, &Ks[bsel][2048 + wid * 512]); \
        gload_lds16(vsrc + (kv0),                   &Vs[bsel][wid * 512]);     \
        gload_lds16(vsrc + 32 * S_ + (kv0),         &Vs[bsel][2048 + wid * 512]); \
    } while (0)

    // Q fragments (pre-scaled by 0.125*log2e): B-operand, 2 qs x 4 k-steps
    bf16x8 qa[2][4];
#pragma unroll
    for (int qs = 0; qs < 2; qs++)
#pragma unroll
        for (int ks = 0; ks < 4; ks++)
            qa[qs][ks] = *(const bf16x8*)(Qg + ((size_t)bh * S_ + q0w + qs * 32 + l31) * HD + ks * 16 + hi * 8);

    const f32x16 z16 = {0.f, 0.f, 0.f, 0.f, 0.f, 0.f, 0.f, 0.f,
                        0.f, 0.f, 0.f, 0.f, 0.f, 0.f, 0.f, 0.f};
    f32x16 o[2][2];                       // [qs][dt]
    o[0][0] = z16; o[0][1] = z16; o[1][0] = z16; o[1][1] = z16;
    f32x4 ls[2] = {{0.f, 0.f, 0.f, 0.f}, {0.f, 0.f, 0.f, 0.f}};

    int cur = 0;
    STAGE(0, 0);
    __syncthreads();

    for (int t = 0; t < S_ / KB; ++t) {
        if (t < S_ / KB - 1) STAGE(cur ^ 1, (t + 1) * KB);

        // S^T (log2 domain): sc[qs][kvt][r] = S[kv=kvt*32+(r&3)+8*(r>>2)+4*hi][q=q0w+qs*32+l31]
        f32x16 sc[2][2];
        __builtin_amdgcn_s_setprio(1);
#pragma unroll
        for (int kvt = 0; kvt < 2; kvt++) {
#pragma unroll
            for (int ks = 0; ks < 4; ks++) {
                bf16x8 kb = *(const bf16x8*)(&Ks[cur][swz(kvt * 32 + l31, ks * 32 + hi * 16)]);
                if (ks == 0) {
                    sc[0][kvt] = __builtin_amdgcn_mfma_f32_32x32x16_bf16(kb, qa[0][0], z16, 0, 0, 0);
                    sc[1][kvt] = __builtin_amdgcn_mfma_f32_32x32x16_bf16(kb, qa[1][0], z16, 0, 0, 0);
                } else {
                    sc[0][kvt] = __builtin_amdgcn_mfma_f32_32x32x16_bf16(kb, qa[0][ks], sc[0][kvt], 0, 0, 0);
                    sc[1][kvt] = __builtin_amdgcn_mfma_f32_32x32x16_bf16(kb, qa[1][ks], sc[1][kvt], 0, 0, 0);
                }
            }
        }
        __builtin_amdgcn_s_setprio(0);

        // hoist V fragments (shared by both qs streams)
        bf16x8 vb[2][4];                  // [dt][kk]
#pragma unroll
        for (int kk = 0; kk < 4; kk++)
#pragma unroll
            for (int dt = 0; dt < 2; dt++)
                vb[dt][kk] = *(const bf16x8*)(&Vs[cur][swz(dt * 32 + l31, kk * 32 + hi * 16)]);

#pragma unroll
        for (int qs = 0; qs < 2; qs++) {
            // ---- softmax: p = exp2(sc); ls += p; pa via cvt_pk + permlane ----
            bf16x8 pa[4];
#pragma unroll
            for (int kvt = 0; kvt < 2; kvt++) {
                float p[16];
#pragma unroll
                for (int r = 0; r < 16; r++) p[r] = __builtin_amdgcn_exp2f(sc[qs][kvt][r]);
                f32x4 s0 = {p[0], p[1], p[2], p[3]};
                f32x4 s1 = {p[4], p[5], p[6], p[7]};
                f32x4 s2 = {p[8], p[9], p[10], p[11]};
                f32x4 s3 = {p[12], p[13], p[14], p[15]};
                ls[qs] += (s0 + s1) + (s2 + s3);
#pragma unroll
                for (int b = 0; b < 2; b++) {
                    unsigned A  = cvt_pk_bf16(p[8 * b + 0], p[8 * b + 1]);
                    unsigned Bw = cvt_pk_bf16(p[8 * b + 4], p[8 * b + 5]);
                    unsigned C  = cvt_pk_bf16(p[8 * b + 2], p[8 * b + 3]);
                    unsigned Dw = cvt_pk_bf16(p[8 * b + 6], p[8 * b + 7]);
                    asm("v_permlane32_swap_b32 %0, %1" : "+v"(A), "+v"(Bw));
                    asm("v_permlane32_swap_b32 %0, %1" : "+v"(C), "+v"(Dw));
                    union { unsigned u[4]; bf16x8 v; } pk;
                    pk.u[0] = A; pk.u[1] = C; pk.u[2] = Bw; pk.u[3] = Dw;
                    pa[kvt * 2 + b] = pk.v;   // B-operand: P[kv=16*(kvt*2+b)+8*hi+j][q]
                }
            }

            // ---- O^T += V^T P ----
            __builtin_amdgcn_s_setprio(1);
#pragma unroll
            for (int kk = 0; kk < 4; kk++) {
#pragma unroll
                for (int dt = 0; dt < 2; dt++)
                    o[qs][dt] = __builtin_amdgcn_mfma_f32_32x32x16_bf16(vb[dt][kk], pa[kk], o[qs][dt], 0, 0, 0);
            }
            __builtin_amdgcn_s_setprio(0);
        }

        __syncthreads();
        cur ^= 1;
    }

    // normalize + write (per qs): own-half sum + other-half sum (same q)
    int b = bh >> 4, h = bh & 15;
#pragma unroll
    for (int qs = 0; qs < 2; qs++) {
        float denom = ls[qs][0] + ls[qs][1] + ls[qs][2] + ls[qs][3];
        denom += __shfl_xor(denom, 32);
        float inv = 1.f / denom;
        int q = q0w + qs * 32 + l31;
        float* obase = out + ((size_t)(b * S_ + q)) * D_ + h * HD;
#pragma unroll
        for (int dt = 0; dt < 2; dt++)
#pragma unroll
            for (int g = 0; g < 4; g++) {
                f32x4 r = {o[qs][dt][4 * g + 0] * inv, o[qs][dt][4 * g + 1] * inv,
                           o[qs][dt][4 * g + 2] * inv, o[qs][dt][4 * g + 3] * inv};
                *(f32x4*)(obase + dt * 32 + 8 * g + 4 * hi) = r;
            }
    }
#undef STAGE
}

extern "C" void kernel_launch(void* const* d_in, const int* in_sizes, int n_in,
                              void* d_out, int out_size, void* d_ws, size_t ws_size,
                              hipStream_t stream) {
    const float* x  = (const float*)d_in[0];
    const float* Wq = (const float*)d_in[1];
    const float* bq = (const float*)d_in[2];
    const float* Wk = (const float*)d_in[3];
    const float* bk = (const float*)d_in[4];
    const float* Wv = (const float*)d_in[5];
    const float* bv = (const float*)d_in[6];
    float* out = (float*)d_out;

    bf16* ws = (bf16*)d_ws;
    bf16* Xb = ws;
    bf16* Wb = Xb + (size_t)B_ * S_ * D_;
    bf16* Qg = Wb + (size_t)3 * D_ * D_;
    bf16* Kg = Qg + (size_t)B_ * S_ * D_;
    bf16* Vt = Kg + (size_t)B_ * S_ * D_;

    hipLaunchKernelGGL(cast_pack_kernel,
                       dim3((B_ * S_ * D_ + 3 * D_ * D_) / (4 * 256)), dim3(256), 0, stream,
                       x, Wq, Wk, Wv, Xb, Wb);
    hipLaunchKernelGGL(gemm_qkv_kernel, dim3(64 * 12), dim3(512), 0, stream,
                       Xb, Wb, bq, bk, bv, Qg, Kg, Vt);
    hipLaunchKernelGGL(attn_kernel, dim3(512), dim3(256), 0, stream,
                       Qg, Kg, Vt, out);
}